// Round 22
// baseline (2291.471 us; speedup 1.0000x reference)
//
#include <hip/hip_runtime.h>

#define N_ROWS 65536
#define IN_DIM 1024
#define HID    2048
#define EMB    256
#define NCODE  4096

typedef __attribute__((ext_vector_type(8))) short bf16x8;
typedef __attribute__((ext_vector_type(4))) float f32x4;

__device__ __forceinline__ unsigned short f2bf(float v) {
    unsigned u = __float_as_uint(v);
    u += 0x7FFFu + ((u >> 16) & 1u);
    return (unsigned short)(u >> 16);
}
__device__ __forceinline__ float bf2f(unsigned short h) {
    return __uint_as_float(((unsigned)h) << 16);
}
// async global->LDS 16B: per-lane global src, wave-uniform LDS base (+lane*16 by HW)
__device__ __forceinline__ void gload16(const unsigned short* g, unsigned short* l) {
    __builtin_amdgcn_global_load_lds(
        (const __attribute__((address_space(1))) unsigned int*)g,
        (__attribute__((address_space(3))) unsigned int*)l, 16, 0, 0);
}

// ---------- weight pre-convert (+transpose) into tiled fragment layout ----------
template<int SPLIT>
__global__ __launch_bounds__(256) void k_conv_w(
    const float* __restrict__ src, unsigned short* __restrict__ dh,
    unsigned short* __restrict__ dl, int NC, int nkt)
{
    const int t = threadIdx.x;
    const int nt = blockIdx.x, kt = blockIdx.y;
    const int kk = t >> 2, j4 = (t & 3) << 2;
    const int k0 = kt << 6, n0 = nt << 4;
    float4 v = *(const float4*)(src + (size_t)(k0 + kk) * NC + n0 + j4);
    size_t tb = ((size_t)nt * nkt + kt) * 1024 + ((kk >> 3) * 128) + (kk & 7);
    float vv[4] = {v.x, v.y, v.z, v.w};
    #pragma unroll
    for (int j = 0; j < 4; ++j) {
        unsigned short h = f2bf(vv[j]);
        dh[tb + (size_t)(j4 + j) * 8] = h;
        if (SPLIT) dl[tb + (size_t)(j4 + j) * 8] = f2bf(vv[j] - bf2f(h));
    }
}

// ---------- row-major A pre-convert -> tiled bf16 hi+lo ----------
__global__ __launch_bounds__(256) void k_conv_a2(
    const float* __restrict__ src, unsigned short* __restrict__ dh,
    unsigned short* __restrict__ dl, int Kw, int nkt)
{
    const int t = threadIdx.x;
    const int mt = blockIdx.x, kt = blockIdx.y;
    const int rr = t >> 4, k4 = (t & 15) << 2;
    float4 v = *(const float4*)(src + (size_t)(mt * 16 + rr) * Kw + kt * 64 + k4);
    size_t addr = ((size_t)mt * nkt + kt) * 1024 + (k4 >> 3) * 128 + rr * 8 + (k4 & 7);
    ushort4 h = { f2bf(v.x), f2bf(v.y), f2bf(v.z), f2bf(v.w) };
    ushort4 lo = { f2bf(v.x - bf2f(h.x)), f2bf(v.y - bf2f(h.y)),
                   f2bf(v.z - bf2f(h.z)), f2bf(v.w - bf2f(h.w)) };
    *(ushort4*)&dh[addr] = h;
    *(ushort4*)&dl[addr] = lo;
}

// ---------- codebook convert (tiled bf16 hi+lo) + 0.5*||c||^2 ----------
__global__ __launch_bounds__(256) void k_conv_cb(
    const float* __restrict__ cb, unsigned short* __restrict__ ch,
    unsigned short* __restrict__ cl_, float* __restrict__ halfsq)
{
    const int t = threadIdx.x;
    const int ct = blockIdx.x;
    const int cl = t >> 4, f = t & 15;
    const int code = (ct << 4) + cl;
    float ssq = 0.f;
    #pragma unroll
    for (int it = 0; it < 4; ++it) {
        const int k4 = (f << 2) + (it << 6);
        float4 v = *(const float4*)(cb + (size_t)code * EMB + k4);
        ssq += v.x * v.x + v.y * v.y + v.z * v.z + v.w * v.w;
        size_t tb = ((size_t)(ct * 4 + (k4 >> 6))) * 1024 + ((k4 >> 3) & 7) * 128 + cl * 8 + (k4 & 7);
        ushort4 h = { f2bf(v.x), f2bf(v.y), f2bf(v.z), f2bf(v.w) };
        *(ushort4*)&ch[tb] = h;
        ushort4 lo = { f2bf(v.x - bf2f(h.x)), f2bf(v.y - bf2f(h.y)),
                       f2bf(v.z - bf2f(h.z)), f2bf(v.w - bf2f(h.w)) };
        *(ushort4*)&cl_[tb] = lo;
    }
    #pragma unroll
    for (int off = 1; off <= 8; off <<= 1) ssq += __shfl_xor(ssq, off);
    if (f == 0) halfsq[code] = 0.5f * ssq;
}

// ---------- GEMM1 special: BM=128, BN=128; TRIPLE buffer, ONE barrier per tile ----------
__global__ __launch_bounds__(512, 1) void k_gemm1(
    const unsigned short* __restrict__ At, const unsigned short* __restrict__ Atl,
    int a_nkt,
    const unsigned short* __restrict__ Bh, const unsigned short* __restrict__ Bl,
    int b_nkt, int K,
    const float* __restrict__ bias,
    unsigned short* __restrict__ outt, unsigned short* __restrict__ outt2,
    int out_nkt)
{
    constexpr int BUFSZ = 16384;
    __shared__ __align__(16) unsigned short s_mem[3 * BUFSZ];   // 96 KB

    const int t = threadIdx.x;
    const int id = blockIdx.x;
    const int m_low = id & 7, rest = id >> 3;
    const int nb = rest & 15;
    const int m0 = (((rest >> 4) << 3) | m_low) * 128;
    const int nb0 = nb * 128;
    const int lane = t & 63, wv = t >> 6;
    const int wm = wv >> 2, wn = wv & 3;
    const int g = lane >> 4, rr = lane & 15;
    const int nt = K >> 6;

    f32x4 acc[4][2];
    #pragma unroll
    for (int mi = 0; mi < 4; ++mi)
        #pragma unroll
        for (int ni = 0; ni < 2; ++ni) acc[mi][ni] = (f32x4){0.f, 0.f, 0.f, 0.f};

    #define G1_STAGE(buf, ktile)                                                       \
        {                                                                              \
            unsigned short* base_ = &s_mem[(buf) * BUFSZ];                             \
            const size_t ga_ = ((size_t)(m0 / 16 + wv) * a_nkt + (ktile)) * 1024;      \
            const size_t gb_ = ((size_t)((nb0 >> 4) + wv) * b_nkt + (ktile)) * 1024;   \
            _Pragma("unroll")                                                          \
            for (int hf = 0; hf < 2; ++hf) {                                           \
                gload16(At + ga_ + hf * 512 + lane * 8, base_ + wv * 1024 + hf * 512); \
                gload16(Bh + gb_ + hf * 512 + lane * 8, base_ + 8192 + wv * 1024 + hf * 512); \
            }                                                                          \
        }

    #define G1_COMPUTE(buf, ktile)                                                     \
        {                                                                              \
            const unsigned short* base_ = &s_mem[(buf) * BUFSZ];                       \
            __builtin_amdgcn_s_setprio(1);                                             \
            _Pragma("unroll")                                                          \
            for (int s = 0; s < 2; ++s) {                                              \
                const int kb = (s << 2) + g;                                           \
                bf16x8 a_h[4], a_l[4], b_h[2], b_l[2];                                 \
                _Pragma("unroll")                                                      \
                for (int i = 0; i < 4; ++i) {                                          \
                    int aaddr = (wm * 4 + i) * 1024 + kb * 128 + (rr << 3);            \
                    a_h[i] = *(const bf16x8*)&base_[aaddr];                            \
                    a_l[i] = *(const bf16x8*)(Atl +                                    \
                        ((size_t)(m0 / 16 + wm * 4 + i) * a_nkt + (ktile)) * 1024      \
                        + kb * 128 + (rr << 3));                                       \
                }                                                                      \
                _Pragma("unroll")                                                      \
                for (int j = 0; j < 2; ++j) {                                          \
                    int baddr = 8192 + (wn * 2 + j) * 1024 + kb * 128 + (rr << 3);     \
                    b_h[j] = *(const bf16x8*)&base_[baddr];                            \
                    b_l[j] = *(const bf16x8*)(Bl +                                     \
                        ((size_t)((nb0 >> 4) + wn * 2 + j) * b_nkt + (ktile)) * 1024   \
                        + kb * 128 + (rr << 3));                                       \
                }                                                                      \
                _Pragma("unroll")                                                      \
                for (int mi = 0; mi < 4; ++mi)                                         \
                    _Pragma("unroll")                                                  \
                    for (int ni = 0; ni < 2; ++ni) {                                   \
                        acc[mi][ni] = __builtin_amdgcn_mfma_f32_16x16x32_bf16(a_h[mi], b_h[ni], acc[mi][ni], 0, 0, 0); \
                        acc[mi][ni] = __builtin_amdgcn_mfma_f32_16x16x32_bf16(a_l[mi], b_h[ni], acc[mi][ni], 0, 0, 0); \
                        acc[mi][ni] = __builtin_amdgcn_mfma_f32_16x16x32_bf16(a_h[mi], b_l[ni], acc[mi][ni], 0, 0, 0); \
                    }                                                                  \
            }                                                                          \
            __builtin_amdgcn_s_setprio(0);                                             \
        }

    G1_STAGE(0, 0)
    int bufc = 0;
    for (int kt = 0; kt < nt; ++kt) {
        const int bufn = (bufc == 2) ? 0 : bufc + 1;
        if (kt + 1 < nt) {
            G1_STAGE(bufn, kt + 1)
            asm volatile("s_waitcnt vmcnt(4)" ::: "memory");
        } else {
            asm volatile("s_waitcnt vmcnt(0)" ::: "memory");
        }
        __builtin_amdgcn_s_barrier();
        __builtin_amdgcn_sched_barrier(0);
        G1_COMPUTE(bufc, kt)
        bufc = bufn;
    }
    #undef G1_STAGE
    #undef G1_COMPUTE
    __builtin_amdgcn_s_barrier();

    for (int pass = 0; pass < 2; ++pass) {
        #pragma unroll
        for (int mi = 0; mi < 4; ++mi)
            #pragma unroll
            for (int ni = 0; ni < 2; ++ni) {
                const int c = wn * 32 + ni * 16 + rr;
                float bb = bias[nb0 + c];
                const int ktl = c >> 6, k = c & 63;
                #pragma unroll
                for (int rg = 0; rg < 4; ++rg) {
                    float v = fmaxf(acc[mi][ni][rg] + bb, 0.f);
                    unsigned short hi = f2bf(v);
                    unsigned short w = (pass == 0) ? hi : f2bf(v - bf2f(hi));
                    int addr = ((wm * 4 + mi) * 2 + ktl) * 1024
                             + ((k >> 3) & 7) * 128 + (g * 4 + rg) * 8 + (k & 7);
                    s_mem[addr] = w;
                }
            }
        __syncthreads();
        unsigned short* dst = (pass == 0) ? outt : outt2;
        #pragma unroll
        for (int it = 0; it < 4; ++it) {
            int f = t + (it << 9);
            int tl = f >> 7, w8 = f & 127;
            size_t gaddr = ((size_t)(m0 / 16 + (tl >> 1)) * out_nkt + (nb0 >> 6) + (tl & 1)) * 1024;
            *(float4*)(dst + gaddr + w8 * 8) = *(const float4*)&s_mem[tl * 1024 + w8 * 8];
        }
        __syncthreads();
    }
}

// ---------- GEMM2 special: BM=64, BN=256, grid=rows/64; TRIPLE buffer, 1 barrier ----------
__global__ __launch_bounds__(512, 1) void k_gemm2(
    const unsigned short* __restrict__ At, const unsigned short* __restrict__ Atl,
    int a_nkt,
    const unsigned short* __restrict__ Bh, const unsigned short* __restrict__ Bl,
    int b_nkt, int K,
    const float* __restrict__ bias, float* __restrict__ out)
{
    constexpr int BUFSZ = 24576;
    __shared__ __align__(16) unsigned short s_mem[3 * BUFSZ];   // 144 KB

    const int t = threadIdx.x;
    const int m0 = blockIdx.x * 64;
    const int lane = t & 63, wv = t >> 6;
    const int wm = wv >> 2, wn = wv & 3;
    const int g = lane >> 4, rr = lane & 15;
    const int nt = K >> 6;

    f32x4 acc[2][4];
    #pragma unroll
    for (int mi = 0; mi < 2; ++mi)
        #pragma unroll
        for (int ni = 0; ni < 4; ++ni) acc[mi][ni] = (f32x4){0.f, 0.f, 0.f, 0.f};

    #define G2_STAGE(buf, ktile)                                                       \
        {                                                                              \
            unsigned short* base_ = &s_mem[(buf) * BUFSZ];                             \
            _Pragma("unroll")                                                          \
            for (int jj = 0; jj < 2; ++jj) {                                           \
                const int j_ = wv * 2 + jj;                                            \
                const size_t gb_ = ((size_t)j_ * b_nkt + (ktile)) * 1024;              \
                _Pragma("unroll")                                                      \
                for (int hf = 0; hf < 2; ++hf)                                         \
                    gload16(Bh + gb_ + hf * 512 + lane * 8,                            \
                            base_ + 8192 + j_ * 1024 + hf * 512);                      \
            }                                                                          \
            const int at_ = wv & 3;                                                    \
            const size_t ga_ = ((size_t)(m0 / 16 + at_) * a_nkt + (ktile)) * 1024;     \
            if (wv < 4) {                                                              \
                _Pragma("unroll")                                                      \
                for (int hf = 0; hf < 2; ++hf)                                         \
                    gload16(At + ga_ + hf * 512 + lane * 8,                            \
                            base_ + at_ * 1024 + hf * 512);                            \
            } else {                                                                   \
                _Pragma("unroll")                                                      \
                for (int hf = 0; hf < 2; ++hf)                                         \
                    gload16(Atl + ga_ + hf * 512 + lane * 8,                           \
                            base_ + 4096 + at_ * 1024 + hf * 512);                     \
            }                                                                          \
        }

    #define G2_COMPUTE(buf, ktile)                                                     \
        {                                                                              \
            const unsigned short* base_ = &s_mem[(buf) * BUFSZ];                       \
            __builtin_amdgcn_s_setprio(1);                                             \
            _Pragma("unroll")                                                          \
            for (int s = 0; s < 2; ++s) {                                              \
                const int kb = (s << 2) + g;                                           \
                bf16x8 a_h[2], a_l[2], b_h[4], b_l[4];                                 \
                _Pragma("unroll")                                                      \
                for (int i = 0; i < 2; ++i) {                                          \
                    int aaddr = (wm * 2 + i) * 1024 + kb * 128 + (rr << 3);            \
                    a_h[i] = *(const bf16x8*)&base_[aaddr];                            \
                    a_l[i] = *(const bf16x8*)&base_[4096 + aaddr];                     \
                }                                                                      \
                _Pragma("unroll")                                                      \
                for (int j = 0; j < 4; ++j) {                                          \
                    int baddr = 8192 + (wn * 4 + j) * 1024 + kb * 128 + (rr << 3);     \
                    b_h[j] = *(const bf16x8*)&base_[baddr];                            \
                    b_l[j] = *(const bf16x8*)(Bl +                                     \
                        ((size_t)(wn * 4 + j) * b_nkt + (ktile)) * 1024                \
                        + kb * 128 + (rr << 3));                                       \
                }                                                                      \
                _Pragma("unroll")                                                      \
                for (int mi = 0; mi < 2; ++mi)                                         \
                    _Pragma("unroll")                                                  \
                    for (int ni = 0; ni < 4; ++ni) {                                   \
                        acc[mi][ni] = __builtin_amdgcn_mfma_f32_16x16x32_bf16(a_h[mi], b_h[ni], acc[mi][ni], 0, 0, 0); \
                        acc[mi][ni] = __builtin_amdgcn_mfma_f32_16x16x32_bf16(a_l[mi], b_h[ni], acc[mi][ni], 0, 0, 0); \
                        acc[mi][ni] = __builtin_amdgcn_mfma_f32_16x16x32_bf16(a_h[mi], b_l[ni], acc[mi][ni], 0, 0, 0); \
                    }                                                                  \
            }                                                                          \
            __builtin_amdgcn_s_setprio(0);                                             \
        }

    G2_STAGE(0, 0)
    int bufc = 0;
    for (int kt = 0; kt < nt; ++kt) {
        const int bufn = (bufc == 2) ? 0 : bufc + 1;
        if (kt + 1 < nt) {
            G2_STAGE(bufn, kt + 1)
            asm volatile("s_waitcnt vmcnt(6)" ::: "memory");
        } else {
            asm volatile("s_waitcnt vmcnt(0)" ::: "memory");
        }
        __builtin_amdgcn_s_barrier();
        __builtin_amdgcn_sched_barrier(0);
        G2_COMPUTE(bufc, kt)
        bufc = bufn;
    }
    #undef G2_STAGE
    #undef G2_COMPUTE
    __builtin_amdgcn_s_barrier();

    float* sf = (float*)s_mem;
    #pragma unroll
    for (int mi = 0; mi < 2; ++mi)
        #pragma unroll
        for (int ni = 0; ni < 4; ++ni)
            #pragma unroll
            for (int rg = 0; rg < 4; ++rg)
                sf[(wm * 32 + mi * 16 + g * 4 + rg) * 256 + wn * 64 + ni * 16 + rr] = acc[mi][ni][rg];
    __syncthreads();
    #pragma unroll
    for (int it = 0; it < 8; ++it) {
        int f = t + (it << 9);
        int r = f >> 6, c4 = (f & 63) << 2;
        float4 v = *(const float4*)&sf[r * 256 + c4];
        v.x += bias[c4 + 0]; v.y += bias[c4 + 1];
        v.z += bias[c4 + 2]; v.w += bias[c4 + 3];
        *(float4*)(out + (size_t)(m0 + r) * EMB + c4) = v;
    }
}

// ---------- MFMA layer: SPLIT -> r15 dbuf loop; !SPLIT AFMT>=1 -> triple-buffer 1-barrier ----------
template<int SPLIT, int AFMT, int OUTT>
__global__ __launch_bounds__(512, 1) void k_layer2(
    const float* __restrict__ A, const unsigned short* __restrict__ At,
    const unsigned short* __restrict__ Atl, int a_nkt,
    int lda, int K,
    const unsigned short* __restrict__ Bh, const unsigned short* __restrict__ Bl,
    int b_nkt, const float* __restrict__ bias, int biasoff,
    float* __restrict__ out, unsigned short* __restrict__ outt,
    unsigned short* __restrict__ outt2,
    int outw, int relu, int init, int ny_log2)
{
    constexpr int BUFSZ = SPLIT ? 32768 : 24576;
    constexpr int NBUF  = SPLIT ? 2 : 3;
    constexpr int AL = 8192;
    constexpr int BH = SPLIT ? 16384 : 8192;
    __shared__ __align__(16) unsigned short s_mem[NBUF * BUFSZ];

    const int t = threadIdx.x;
    const int id = blockIdx.x;
    const int m_low = id & 7, rest = id >> 3;
    const int nb = rest & ((1 << ny_log2) - 1);
    const int m0 = (((rest >> ny_log2) << 3) | m_low) * 128;
    const int nb0 = nb * 256;
    const int lane = t & 63, wv = t >> 6;
    const int wm = wv >> 2, wn = wv & 3;
    const int g = lane >> 4, rr = lane & 15;
    const int nt = K >> 6;

    f32x4 acc[4][4];
    #pragma unroll
    for (int mi = 0; mi < 4; ++mi)
        #pragma unroll
        for (int ni = 0; ni < 4; ++ni) acc[mi][ni] = (f32x4){0.f, 0.f, 0.f, 0.f};

    #define STAGE_DMA(buf, ktile)                                                      \
        {                                                                              \
            unsigned short* base_ = &s_mem[(buf) * BUFSZ];                             \
            _Pragma("unroll")                                                          \
            for (int jj = 0; jj < 2; ++jj) {                                           \
                const int j_ = wv * 2 + jj;                                            \
                const size_t gt_ = ((size_t)(nb0 / 16 + j_) * b_nkt + (ktile)) * 1024; \
                _Pragma("unroll")                                                      \
                for (int hf = 0; hf < 2; ++hf)                                         \
                    gload16(Bh + gt_ + hf * 512 + lane * 8,                            \
                            base_ + BH + j_ * 1024 + hf * 512);                        \
            }                                                                          \
            if (AFMT >= 1) {                                                           \
                const size_t ga_ = ((size_t)(m0 / 16 + wv) * a_nkt + (ktile)) * 1024;  \
                _Pragma("unroll")                                                      \
                for (int hf = 0; hf < 2; ++hf)                                         \
                    gload16(At + ga_ + hf * 512 + lane * 8,                            \
                            base_ + wv * 1024 + hf * 512);                             \
                if (AFMT == 2) {                                                       \
                    _Pragma("unroll")                                                  \
                    for (int hf = 0; hf < 2; ++hf)                                     \
                        gload16(Atl + ga_ + hf * 512 + lane * 8,                       \
                                base_ + AL + wv * 1024 + hf * 512);                    \
                }                                                                      \
            }                                                                          \
        }

    #define A_LOAD(ktile, pv)                                                          \
        {                                                                              \
            _Pragma("unroll")                                                          \
            for (int it = 0; it < 4; ++it) {                                           \
                int f_ = t + (it << 9);                                                \
                int r_ = f_ >> 4, k4_ = (f_ & 15) << 2;                                \
                pv[it] = *(const float4*)(A + (size_t)(m0 + r_) * lda + (ktile) * 64 + k4_); \
            }                                                                          \
        }

    #define A_WRITE(buf, pv)                                                           \
        {                                                                              \
            unsigned short* base_ = &s_mem[(buf) * BUFSZ];                             \
            _Pragma("unroll")                                                          \
            for (int it = 0; it < 4; ++it) {                                           \
                int f_ = t + (it << 9);                                                \
                int r_ = f_ >> 4, k4_ = (f_ & 15) << 2;                                \
                int mt_ = r_ >> 4, rl_ = r_ & 15, kb_ = k4_ >> 3, e_ = k4_ & 7;        \
                int addr_ = mt_ * 1024 + kb_ * 128 + ((rl_ ^ kb_) << 3) + e_;          \
                float4 v_ = pv[it];                                                    \
                ushort4 hi_, lo_;                                                      \
                hi_.x = f2bf(v_.x); hi_.y = f2bf(v_.y); hi_.z = f2bf(v_.z); hi_.w = f2bf(v_.w); \
                *(ushort4*)&base_[addr_] = hi_;                                        \
                if (SPLIT) {                                                           \
                    lo_.x = f2bf(v_.x - bf2f(hi_.x)); lo_.y = f2bf(v_.y - bf2f(hi_.y)); \
                    lo_.z = f2bf(v_.z - bf2f(hi_.z)); lo_.w = f2bf(v_.w - bf2f(hi_.w)); \
                    *(ushort4*)&base_[AL + addr_] = lo_;                               \
                }                                                                      \
            }                                                                          \
        }

    #define COMPUTE(buf, ktile)                                                        \
        {                                                                              \
            const unsigned short* base_ = &s_mem[(buf) * BUFSZ];                       \
            __builtin_amdgcn_s_setprio(1);                                             \
            _Pragma("unroll")                                                          \
            for (int s = 0; s < 2; ++s) {                                              \
                const int kb = (s << 2) + g;                                           \
                bf16x8 a_h[4], a_l[4], b_h[4], b_l[4];                                 \
                _Pragma("unroll")                                                      \
                for (int i = 0; i < 4; ++i) {                                          \
                    int arow = (AFMT == 0) ? (((rr ^ kb) & 15) << 3) : (rr << 3);      \
                    int aaddr = (wm * 4 + i) * 1024 + kb * 128 + arow;                 \
                    a_h[i] = *(const bf16x8*)&base_[aaddr];                            \
                    if (SPLIT) a_l[i] = *(const bf16x8*)&base_[AL + aaddr];            \
                    int baddr = (wn * 4 + i) * 1024 + kb * 128 + (rr << 3);            \
                    b_h[i] = *(const bf16x8*)&base_[BH + baddr];                       \
                    if (SPLIT)                                                         \
                        b_l[i] = *(const bf16x8*)(Bl +                                 \
                            ((size_t)(nb0 / 16 + wn * 4 + i) * b_nkt + (ktile)) * 1024 \
                            + kb * 128 + (rr << 3));                                   \
                }                                                                      \
                _Pragma("unroll")                                                      \
                for (int mi = 0; mi < 4; ++mi)                                         \
                    _Pragma("unroll")                                                  \
                    for (int ni = 0; ni < 4; ++ni) {                                   \
                        acc[mi][ni] = __builtin_amdgcn_mfma_f32_16x16x32_bf16(a_h[mi], b_h[ni], acc[mi][ni], 0, 0, 0); \
                        if (SPLIT) {                                                   \
                            acc[mi][ni] = __builtin_amdgcn_mfma_f32_16x16x32_bf16(a_l[mi], b_h[ni], acc[mi][ni], 0, 0, 0); \
                            acc[mi][ni] = __builtin_amdgcn_mfma_f32_16x16x32_bf16(a_h[mi], b_l[ni], acc[mi][ni], 0, 0, 0); \
                        }                                                              \
                    }                                                                  \
            }                                                                          \
            __builtin_amdgcn_s_setprio(0);                                             \
        }

    if (SPLIT || AFMT == 0) {
        float4 pv[4];
        STAGE_DMA(0, 0)
        if (AFMT == 0) {
            A_LOAD(0, pv)
            A_WRITE(0, pv)
        }
        asm volatile("s_waitcnt vmcnt(0) lgkmcnt(0)" ::: "memory");
        __builtin_amdgcn_s_barrier();
        __builtin_amdgcn_sched_barrier(0);
        int cur = 0;
        for (int kt = 0; kt < nt; ++kt) {
            if (kt + 1 < nt) {
                STAGE_DMA(cur ^ 1, kt + 1)
                if (AFMT == 0) A_LOAD(kt + 1, pv)
            }
            COMPUTE(cur, kt)
            if (AFMT == 0) { if (kt + 1 < nt) A_WRITE(cur ^ 1, pv) }
            asm volatile("s_waitcnt vmcnt(0) lgkmcnt(0)" ::: "memory");
            __builtin_amdgcn_s_barrier();
            __builtin_amdgcn_sched_barrier(0);
            cur ^= 1;
        }
    } else {
        STAGE_DMA(0, 0)
        int bufc = 0;
        for (int kt = 0; kt < nt; ++kt) {
            const int bufn = (bufc == 2) ? 0 : bufc + 1;
            if (kt + 1 < nt) {
                STAGE_DMA(bufn, kt + 1)
                asm volatile("s_waitcnt vmcnt(6)" ::: "memory");
            } else {
                asm volatile("s_waitcnt vmcnt(0)" ::: "memory");
            }
            __builtin_amdgcn_s_barrier();
            __builtin_amdgcn_sched_barrier(0);
            COMPUTE(bufc, kt)
            bufc = bufn;
        }
        __builtin_amdgcn_s_barrier();
    }
    #undef STAGE_DMA
    #undef A_LOAD
    #undef A_WRITE
    #undef COMPUTE

    if (OUTT == 0) {
        float* sf = (float*)s_mem;
        for (int rm = 0; rm < 2; ++rm) {
            if (wm == rm) {
                #pragma unroll
                for (int mi = 0; mi < 4; ++mi)
                    #pragma unroll
                    for (int ni = 0; ni < 4; ++ni)
                        #pragma unroll
                        for (int rg = 0; rg < 4; ++rg)
                            sf[(mi * 16 + g * 4 + rg) * 256 + wn * 64 + ni * 16 + rr] = acc[mi][ni][rg];
            }
            __syncthreads();
            #pragma unroll
            for (int it = 0; it < 8; ++it) {
                int f = t + (it << 9);
                int r = f >> 6, c4 = (f & 63) << 2;
                float4 v = *(const float4*)&sf[r * 256 + c4];
                int gr = m0 + rm * 64 + r, gc = nb0 + c4;
                float* op = out + (size_t)gr * outw + gc;
                if (init) {
                    v.x += bias[biasoff + gc + 0]; v.y += bias[biasoff + gc + 1];
                    v.z += bias[biasoff + gc + 2]; v.w += bias[biasoff + gc + 3];
                } else {
                    float4 o = *(const float4*)op;
                    v.x += o.x; v.y += o.y; v.z += o.z; v.w += o.w;
                }
                if (relu) {
                    v.x = fmaxf(v.x, 0.f); v.y = fmaxf(v.y, 0.f);
                    v.z = fmaxf(v.z, 0.f); v.w = fmaxf(v.w, 0.f);
                }
                *(float4*)op = v;
            }
            __syncthreads();
        }
    } else {
        const int npass = (OUTT == 2) ? 2 : 1;
        for (int pass = 0; pass < npass; ++pass) {
            #pragma unroll
            for (int mi = 0; mi < 4; ++mi)
                #pragma unroll
                for (int ni = 0; ni < 4; ++ni) {
                    const int c = wn * 64 + ni * 16 + rr;
                    float bb = bias[biasoff + nb0 + c];
                    #pragma unroll
                    for (int rg = 0; rg < 4; ++rg) {
                        float v = acc[mi][ni][rg] + bb;
                        if (relu) v = fmaxf(v, 0.f);
                        unsigned short hi = f2bf(v);
                        unsigned short w = (pass == 0) ? hi : f2bf(v - bf2f(hi));
                        int addr = ((wm * 4 + mi) * 4 + wn) * 1024
                                 + (ni * 2 + (rr >> 3)) * 128 + (g * 4 + rg) * 8 + (rr & 7);
                        s_mem[addr] = w;
                    }
                }
            __syncthreads();
            unsigned short* dst = (pass == 0) ? outt : outt2;
            #pragma unroll
            for (int it = 0; it < 8; ++it) {
                int f = t + (it << 9);
                int tl = f >> 7, w8 = f & 127;
                size_t gaddr = ((size_t)(m0 / 16 + (tl >> 2)) * outw + nb0 / 64 + (tl & 3)) * 1024;
                *(float4*)(dst + gaddr + w8 * 8) = *(const float4*)&s_mem[tl * 1024 + w8 * 8];
            }
            __syncthreads();
        }
    }
}

// ---------- distance argmin v8 (r20): TRIPLE-buffered scan, ONE barrier per chunk ----------
__global__ __launch_bounds__(512, 1) void k_dist(
    float* encq, const unsigned short* __restrict__ ch,
    const unsigned short* __restrict__ cl,
    const float* __restrict__ hsq, const float* __restrict__ cb,
    unsigned short* __restrict__ qt)
{
    __shared__ __align__(16) unsigned short s_cb[3][16384];   // 96 KB
    __shared__ int s_c1[256], s_c2[256];

    const int t = threadIdx.x;
    const int lane = t & 63, wv = t >> 6;
    const int g = lane >> 4, rr = lane & 15;
    const int r0 = blockIdx.x * 256;

    bf16x8 eh[2][8], el[2][8];
    #pragma unroll
    for (int rg = 0; rg < 2; ++rg) {
        const float* ep = encq + (size_t)(r0 + wv * 32 + rg * 16 + rr) * EMB + g * 8;
        #pragma unroll
        for (int s = 0; s < 8; ++s) {
            float4 v0 = *(const float4*)(ep + s * 32);
            float4 v1 = *(const float4*)(ep + s * 32 + 4);
            float vv[8] = {v0.x, v0.y, v0.z, v0.w, v1.x, v1.y, v1.z, v1.w};
            bf16x8 a, b;
            #pragma unroll
            for (int j = 0; j < 8; ++j) {
                unsigned short h = f2bf(vv[j]);
                a[j] = (short)h;
                b[j] = (short)f2bf(vv[j] - bf2f(h));
            }
            eh[rg][s] = a; el[rg][s] = b;
        }
    }
    float b1v[2][4], b2v[2][4]; int i1v[2][4], i2v[2][4];
    #pragma unroll
    for (int rg = 0; rg < 2; ++rg)
        #pragma unroll
        for (int r2 = 0; r2 < 4; ++r2) {
            b1v[rg][r2] = -1e30f; b2v[rg][r2] = -1e30f;
            i1v[rg][r2] = 0; i2v[rg][r2] = 0;
        }

    #define STAGE(buf, c)                                                              \
        {                                                                              \
            const unsigned short* gh_ = ch + (size_t)(c) * 8192 + wv * 1024;           \
            const unsigned short* gl_ = cl + (size_t)(c) * 8192 + wv * 1024;           \
            _Pragma("unroll")                                                          \
            for (int i_ = 0; i_ < 2; ++i_) {                                           \
                gload16(gh_ + i_ * 512 + lane * 8, &s_cb[buf][wv * 1024 + i_ * 512]);  \
                gload16(gl_ + i_ * 512 + lane * 8, &s_cb[buf][8192 + wv * 1024 + i_ * 512]); \
            }                                                                          \
        }

    #define COMPUTE(cur, c, hv_)                                                       \
        {                                                                              \
            f32x4 ahh[2][2], ahl[2][2], alh[2][2];                                     \
            _Pragma("unroll")                                                          \
            for (int rg = 0; rg < 2; ++rg)                                             \
                _Pragma("unroll")                                                      \
                for (int ci = 0; ci < 2; ++ci) {                                       \
                    ahh[rg][ci] = (f32x4){0.f, 0.f, 0.f, 0.f};                         \
                    ahl[rg][ci] = (f32x4){0.f, 0.f, 0.f, 0.f};                         \
                    alh[rg][ci] = (f32x4){0.f, 0.f, 0.f, 0.f};                         \
                }                                                                      \
            __builtin_amdgcn_s_setprio(1);                                             \
            _Pragma("unroll")                                                          \
            for (int s = 0; s < 8; ++s) {                                              \
                const int ktile = s >> 1, kb = ((s & 1) << 2) + g;                     \
                _Pragma("unroll")                                                      \
                for (int ci = 0; ci < 2; ++ci) {                                       \
                    const int off = (ci * 4 + ktile) * 1024 + kb * 128 + rr * 8;       \
                    bf16x8 bh = *(const bf16x8*)&s_cb[cur][off];                       \
                    bf16x8 bl = *(const bf16x8*)&s_cb[cur][8192 + off];                \
                    _Pragma("unroll")                                                  \
                    for (int rg = 0; rg < 2; ++rg) {                                   \
                        ahh[rg][ci] = __builtin_amdgcn_mfma_f32_16x16x32_bf16(eh[rg][s], bh, ahh[rg][ci], 0, 0, 0); \
                        ahl[rg][ci] = __builtin_amdgcn_mfma_f32_16x16x32_bf16(eh[rg][s], bl, ahl[rg][ci], 0, 0, 0); \
                        alh[rg][ci] = __builtin_amdgcn_mfma_f32_16x16x32_bf16(el[rg][s], bh, alh[rg][ci], 0, 0, 0); \
                    }                                                                  \
                }                                                                      \
            }                                                                          \
            __builtin_amdgcn_s_setprio(0);                                             \
            _Pragma("unroll")                                                          \
            for (int rg = 0; rg < 2; ++rg)                                             \
                _Pragma("unroll")                                                      \
                for (int ci = 0; ci < 2; ++ci) {                                       \
                    f32x4 av = ahh[rg][ci] + ahl[rg][ci] + alh[rg][ci];                \
                    const int code = ((c) << 5) + (ci << 4) + rr;                      \
                    const float hs = __shfl(hv_, ci * 16 + rr);                        \
                    _Pragma("unroll")                                                  \
                    for (int r2 = 0; r2 < 4; ++r2) {                                   \
                        float v = av[r2] - hs;                                         \
                        bool bt1 = (v > b1v[rg][r2]) || (v == b1v[rg][r2] && code < i1v[rg][r2]); \
                        bool bt2 = (v > b2v[rg][r2]) || (v == b2v[rg][r2] && code < i2v[rg][r2]); \
                        if (bt1) { b2v[rg][r2] = b1v[rg][r2]; i2v[rg][r2] = i1v[rg][r2]; \
                                   b1v[rg][r2] = v; i1v[rg][r2] = code; }              \
                        else if (bt2) { b2v[rg][r2] = v; i2v[rg][r2] = code; }         \
                    }                                                                  \
                }                                                                      \
        }

    STAGE(0, 0)
    int bufc = 0;
    for (int c = 0; c < 128; ++c) {
        const int bufn = (bufc == 2) ? 0 : bufc + 1;
        if (c + 1 < 128) STAGE(bufn, c + 1)
        float hv_ = hsq[(c << 5) + (lane & 31)];
        if (c + 1 < 128) asm volatile("s_waitcnt vmcnt(5)" ::: "memory");
        else             asm volatile("s_waitcnt vmcnt(0)" ::: "memory");
        __builtin_amdgcn_s_barrier();
        __builtin_amdgcn_sched_barrier(0);
        COMPUTE(bufc, c, hv_)
        bufc = bufn;
    }
    #undef STAGE
    #undef COMPUTE

    #pragma unroll
    for (int off = 1; off <= 8; off <<= 1) {
        #pragma unroll
        for (int rg = 0; rg < 2; ++rg)
            #pragma unroll
            for (int r2 = 0; r2 < 4; ++r2) {
                float ob1 = __shfl_xor(b1v[rg][r2], off), ob2 = __shfl_xor(b2v[rg][r2], off);
                int oi1 = __shfl_xor(i1v[rg][r2], off), oi2 = __shfl_xor(i2v[rg][r2], off);
                bool ofirst = (ob1 > b1v[rg][r2]) || (ob1 == b1v[rg][r2] && oi1 < i1v[rg][r2]);
                if (ofirst) {
                    bool mysec = (b1v[rg][r2] > ob2) || (b1v[rg][r2] == ob2 && i1v[rg][r2] < oi2);
                    b2v[rg][r2] = mysec ? b1v[rg][r2] : ob2; i2v[rg][r2] = mysec ? i1v[rg][r2] : oi2;
                    b1v[rg][r2] = ob1; i1v[rg][r2] = oi1;
                } else {
                    bool osec = (ob1 > b2v[rg][r2]) || (ob1 == b2v[rg][r2] && oi1 < i2v[rg][r2]);
                    b2v[rg][r2] = osec ? ob1 : b2v[rg][r2]; i2v[rg][r2] = osec ? oi1 : i2v[rg][r2];
                }
            }
    }
    if (rr == 0) {
        #pragma unroll
        for (int rg = 0; rg < 2; ++rg)
            #pragma unroll
            for (int r2 = 0; r2 < 4; ++r2) {
                int rl = wv * 32 + rg * 16 + g * 4 + r2;
                s_c1[rl] = i1v[rg][r2]; s_c2[rl] = i2v[rg][r2];
            }
    }
    __syncthreads();

    for (int rloc = 0; rloc < 32; ++rloc) {
        const int row = wv * 32 + rloc;
        const int c1 = s_c1[row], c2 = s_c2[row];
        float4 ev = *(const float4*)(encq + (size_t)(r0 + row) * EMB + lane * 4);
        float4 v1 = *(const float4*)(cb + (size_t)c1 * EMB + lane * 4);
        float4 v2 = *(const float4*)(cb + (size_t)c2 * EMB + lane * 4);
        float d1 = ev.x * v1.x + ev.y * v1.y + ev.z * v1.z + ev.w * v1.w;
        float d2 = ev.x * v2.x + ev.y * v2.y + ev.z * v2.z + ev.w * v2.w;
        #pragma unroll
        for (int off = 1; off <= 32; off <<= 1) {
            d1 += __shfl_xor(d1, off);
            d2 += __shfl_xor(d2, off);
        }
        if (lane == 0) {
            float s1 = d1 - hsq[c1], s2 = d2 - hsq[c2];
            bool keep1 = (s1 > s2) || (s1 == s2 && c1 < c2);
            s_c1[row] = keep1 ? c1 : c2;
        }
    }
    __syncthreads();
    #pragma unroll
    for (int it = 0; it < 32; ++it) {
        int f = t + (it << 9);
        int row = f >> 6, c4 = (f & 63) << 2;
        int bi = s_c1[row];
        float4 qv = *(const float4*)(cb + (size_t)bi * EMB + c4);
        const int R = r0 + row;
        *(float4*)(encq + (size_t)R * EMB + c4) = qv;
        const int k4 = c4 & 63;
        size_t qaddr = ((size_t)(R >> 4) * 4 + (c4 >> 6)) * 1024
                     + (k4 >> 3) * 128 + (R & 15) * 8 + (k4 & 7);
        ushort4 qh = { f2bf(qv.x), f2bf(qv.y), f2bf(qv.z), f2bf(qv.w) };
        *(ushort4*)&qt[qaddr] = qh;
    }
}

// ---------- fallback fp32 decoder ----------
__global__ __launch_bounds__(256) void k_dec_fb(
    const float* __restrict__ qz,
    const float* __restrict__ W3, const float* __restrict__ b3,
    const float* __restrict__ W4, const float* __restrict__ b4,
    float* __restrict__ outd) {
    __shared__ float s_q[8][EMB];
    __shared__ float s_h2[8][HID];
    const int t = threadIdx.x;
    const int row0 = blockIdx.x * 8;
    #pragma unroll
    for (int r = 0; r < 8; ++r) s_q[r][t] = qz[(size_t)(row0 + r) * EMB + t];
    __syncthreads();
    for (int gg = 0; gg < 8; ++gg) {
        const int j = (gg << 8) + t;
        float acc[8];
        #pragma unroll
        for (int r = 0; r < 8; ++r) acc[r] = 0.f;
        const float* wp = W3 + j;
        for (int e = 0; e < EMB; e += 4) {
            const float w0 = wp[(size_t)(e + 0) * HID];
            const float w1v = wp[(size_t)(e + 1) * HID];
            const float w2v = wp[(size_t)(e + 2) * HID];
            const float w3v = wp[(size_t)(e + 3) * HID];
            #pragma unroll
            for (int r = 0; r < 8; ++r) {
                const float4 qv = *reinterpret_cast<const float4*>(&s_q[r][e]);
                acc[r] = fmaf(qv.x, w0, acc[r]);
                acc[r] = fmaf(qv.y, w1v, acc[r]);
                acc[r] = fmaf(qv.z, w2v, acc[r]);
                acc[r] = fmaf(qv.w, w3v, acc[r]);
            }
        }
        const float bb = b3[j];
        #pragma unroll
        for (int r = 0; r < 8; ++r) s_h2[r][j] = fmaxf(acc[r] + bb, 0.f);
    }
    __syncthreads();
    float acc4[8][4];
    #pragma unroll
    for (int r = 0; r < 8; ++r)
        #pragma unroll
        for (int ci = 0; ci < 4; ++ci) acc4[r][ci] = 0.f;
    const float* w4p = W4 + t;
    for (int k = 0; k < HID; k += 4) {
        float wv[4][4];
        #pragma unroll
        for (int ki = 0; ki < 4; ++ki)
            #pragma unroll
            for (int ci = 0; ci < 4; ++ci)
                wv[ki][ci] = w4p[(size_t)(k + ki) * IN_DIM + (ci << 8)];
        #pragma unroll
        for (int r = 0; r < 8; ++r) {
            const float4 hv = *reinterpret_cast<const float4*>(&s_h2[r][k]);
            #pragma unroll
            for (int ci = 0; ci < 4; ++ci) {
                acc4[r][ci] = fmaf(hv.x, wv[0][ci], acc4[r][ci]);
                acc4[r][ci] = fmaf(hv.y, wv[1][ci], acc4[r][ci]);
                acc4[r][ci] = fmaf(hv.z, wv[2][ci], acc4[r][ci]);
                acc4[r][ci] = fmaf(hv.w, wv[3][ci], acc4[r][ci]);
            }
        }
    }
    #pragma unroll
    for (int ci = 0; ci < 4; ++ci) {
        const float bb = b4[(ci << 8) + t];
        #pragma unroll
        for (int r = 0; r < 8; ++r)
            outd[(size_t)(row0 + r) * IN_DIM + (ci << 8) + t] = acc4[r][ci] + bb;
    }
}

extern "C" void kernel_launch(void* const* d_in, const int* in_sizes, int n_in,
                              void* d_out, int out_size, void* d_ws, size_t ws_size,
                              hipStream_t stream) {
    const float* x  = (const float*)d_in[0];
    const float* W1 = (const float*)d_in[1];
    const float* b1 = (const float*)d_in[2];
    const float* W2 = (const float*)d_in[3];
    const float* b2 = (const float*)d_in[4];
    const float* cb = (const float*)d_in[5];
    const float* W3 = (const float*)d_in[6];
    const float* b3 = (const float*)d_in[7];
    const float* W4 = (const float*)d_in[8];
    const float* b4 = (const float*)d_in[9];

    float* outq = (float*)d_out;                       // [N,256]
    float* outd = outq + (size_t)N_ROWS * EMB;         // [N,1024]

    // scratch in the decoded-output region (dead before GEMM4 writes it)
    unsigned short* ou = (unsigned short*)outd;
    unsigned short* W1Th = ou;                         // 2M ushort
    unsigned short* W1Tl = ou + 2097152;               // 2M
    unsigned short* W2Th = ou + 4194304;               // 512K
    unsigned short* W2Tl = ou + 4718592;               // 512K
    unsigned short* cbh  = ou + 5242880;               // 1M
    unsigned short* cbl  = ou + 6291456;               // 1M
    float* halfsq = outd + 3670016;                    // 4K floats
    unsigned short* h_hi = (unsigned short*)(outd + 4194304);   // 64 MB (strip)
    unsigned short* h_lo = h_hi + 33554432;                     // 64 MB (strip)
    unsigned short* qt = (unsigned short*)(outd + 58720256);    // 32 MB, tail
    float* enc = outq;                                 // consumed by k_dist

    // d_ws: W3T (1MB) + W4T (4MB) + 64MB region (xt during encoder, h2t during decoder)
    const bool fastdec = ws_size >= (size_t)72351744;
    unsigned short* W3Th = (unsigned short*)d_ws;
    unsigned short* W4Th = W3Th + 524288;
    unsigned short* h2t  = (unsigned short*)((char*)d_ws + 5242880);
    unsigned short* xt_hi = h2t;                       // 32 MB (encoder strips)
    unsigned short* xt_lo = h2t + 16777216;            // 32 MB

    // prep: weight/codebook conversion
    k_conv_w<1><<<dim3(128, 16), 256, 0, stream>>>(W1, W1Th, W1Tl, HID, 16);
    k_conv_w<1><<<dim3(16, 32), 256, 0, stream>>>(W2, W2Th, W2Tl, EMB, 32);
    k_conv_cb<<<256, 256, 0, stream>>>(cb, cbh, cbl, halfsq);
    if (fastdec) {
        k_conv_w<0><<<dim3(128, 4), 256, 0, stream>>>(W3, W3Th, nullptr, HID, 4);
        k_conv_w<0><<<dim3(64, 32), 256, 0, stream>>>(W4, W4Th, nullptr, IN_DIM, 32);
    }
    if (fastdec) {
        for (int s = 0; s < 4; ++s) {
            k_conv_a2<<<dim3(1024, 16), 256, 0, stream>>>(
                x + (size_t)s * 16777216, xt_hi, xt_lo, IN_DIM, 16);
            k_gemm1<<<2048, 512, 0, stream>>>(
                xt_hi, xt_lo, 16, W1Th, W1Tl, 16, IN_DIM, b1, h_hi, h_lo, 32);
            k_gemm2<<<256, 512, 0, stream>>>(
                h_hi, h_lo, 32, W2Th, W2Tl, 32, HID, b2,
                enc + (size_t)s * 4194304);
        }
    } else {
        for (int q = 0; q < 4; ++q) {
            k_layer2<1, 0, 2><<<1024, 512, 0, stream>>>(
                x, nullptr, nullptr, 0, IN_DIM, IN_DIM,
                W1Th + (size_t)q * 524288, W1Tl + (size_t)q * 524288, 16,
                b1, q * 512, nullptr, h_hi, h_lo, 8, 1, 0, 1);
            k_layer2<1, 2, 0><<<512, 512, 0, stream>>>(
                nullptr, h_hi, h_lo, 8, 0, 512,
                W2Th + (size_t)q * 8192, W2Tl + (size_t)q * 8192, 32,
                b2, 0, enc, nullptr, nullptr, EMB, 0, q == 0, 0);
        }
    }
    // nearest-code + gather (writes quantized output + tiled q for the decoder)
    k_dist<<<256, 512, 0, stream>>>(enc, cbh, cbl, halfsq, cb, qt);
    // decoder: 4 m-strips, single-pass GEMM4 (triple-buffer 1-barrier loops)
    if (fastdec) {
        for (int s = 0; s < 4; ++s) {
            const size_t roff = (size_t)s * 16384;
            k_layer2<0, 1, 1><<<1024, 512, 0, stream>>>(
                nullptr, qt + (size_t)s * 4194304, nullptr, 4, 0, EMB,
                W3Th, nullptr, 4,
                b3, 0, nullptr, h2t, nullptr, 32, 1, 0, 3);
            k_layer2<0, 1, 0><<<512, 512, 0, stream>>>(
                nullptr, h2t, nullptr, 32, 0, HID,
                W4Th, nullptr, 32,
                b4, 0, outd + roff * IN_DIM, nullptr, nullptr, IN_DIM, 0, 1, 2);
        }
    } else {
        k_dec_fb<<<N_ROWS / 8, 256, 0, stream>>>(outq, W3, b3, W4, b4, outd);
    }
}

// Round 23
// 2149.729 us; speedup vs baseline: 1.0659x; 1.0659x over previous
//
#include <hip/hip_runtime.h>

#define N_ROWS 65536
#define IN_DIM 1024
#define HID    2048
#define EMB    256
#define NCODE  4096

typedef __attribute__((ext_vector_type(8))) short bf16x8;
typedef __attribute__((ext_vector_type(4))) float f32x4;

__device__ __forceinline__ unsigned short f2bf(float v) {
    unsigned u = __float_as_uint(v);
    u += 0x7FFFu + ((u >> 16) & 1u);
    return (unsigned short)(u >> 16);
}
__device__ __forceinline__ float bf2f(unsigned short h) {
    return __uint_as_float(((unsigned)h) << 16);
}
// async global->LDS 16B: per-lane global src, wave-uniform LDS base (+lane*16 by HW)
__device__ __forceinline__ void gload16(const unsigned short* g, unsigned short* l) {
    __builtin_amdgcn_global_load_lds(
        (const __attribute__((address_space(1))) unsigned int*)g,
        (__attribute__((address_space(3))) unsigned int*)l, 16, 0, 0);
}

// ---------- weight pre-convert (+transpose) into tiled fragment layout ----------
template<int SPLIT>
__global__ __launch_bounds__(256) void k_conv_w(
    const float* __restrict__ src, unsigned short* __restrict__ dh,
    unsigned short* __restrict__ dl, int NC, int nkt)
{
    const int t = threadIdx.x;
    const int nt = blockIdx.x, kt = blockIdx.y;
    const int kk = t >> 2, j4 = (t & 3) << 2;
    const int k0 = kt << 6, n0 = nt << 4;
    float4 v = *(const float4*)(src + (size_t)(k0 + kk) * NC + n0 + j4);
    size_t tb = ((size_t)nt * nkt + kt) * 1024 + ((kk >> 3) * 128) + (kk & 7);
    float vv[4] = {v.x, v.y, v.z, v.w};
    #pragma unroll
    for (int j = 0; j < 4; ++j) {
        unsigned short h = f2bf(vv[j]);
        dh[tb + (size_t)(j4 + j) * 8] = h;
        if (SPLIT) dl[tb + (size_t)(j4 + j) * 8] = f2bf(vv[j] - bf2f(h));
    }
}

// ---------- row-major A pre-convert -> tiled bf16 hi+lo ----------
__global__ __launch_bounds__(256) void k_conv_a2(
    const float* __restrict__ src, unsigned short* __restrict__ dh,
    unsigned short* __restrict__ dl, int Kw, int nkt)
{
    const int t = threadIdx.x;
    const int mt = blockIdx.x, kt = blockIdx.y;
    const int rr = t >> 4, k4 = (t & 15) << 2;
    float4 v = *(const float4*)(src + (size_t)(mt * 16 + rr) * Kw + kt * 64 + k4);
    size_t addr = ((size_t)mt * nkt + kt) * 1024 + (k4 >> 3) * 128 + rr * 8 + (k4 & 7);
    ushort4 h = { f2bf(v.x), f2bf(v.y), f2bf(v.z), f2bf(v.w) };
    ushort4 lo = { f2bf(v.x - bf2f(h.x)), f2bf(v.y - bf2f(h.y)),
                   f2bf(v.z - bf2f(h.z)), f2bf(v.w - bf2f(h.w)) };
    *(ushort4*)&dh[addr] = h;
    *(ushort4*)&dl[addr] = lo;
}

// ---------- codebook convert (tiled bf16 hi+lo) + 0.5*||c||^2 ----------
__global__ __launch_bounds__(256) void k_conv_cb(
    const float* __restrict__ cb, unsigned short* __restrict__ ch,
    unsigned short* __restrict__ cl_, float* __restrict__ halfsq)
{
    const int t = threadIdx.x;
    const int ct = blockIdx.x;
    const int cl = t >> 4, f = t & 15;
    const int code = (ct << 4) + cl;
    float ssq = 0.f;
    #pragma unroll
    for (int it = 0; it < 4; ++it) {
        const int k4 = (f << 2) + (it << 6);
        float4 v = *(const float4*)(cb + (size_t)code * EMB + k4);
        ssq += v.x * v.x + v.y * v.y + v.z * v.z + v.w * v.w;
        size_t tb = ((size_t)(ct * 4 + (k4 >> 6))) * 1024 + ((k4 >> 3) & 7) * 128 + cl * 8 + (k4 & 7);
        ushort4 h = { f2bf(v.x), f2bf(v.y), f2bf(v.z), f2bf(v.w) };
        *(ushort4*)&ch[tb] = h;
        ushort4 lo = { f2bf(v.x - bf2f(h.x)), f2bf(v.y - bf2f(h.y)),
                       f2bf(v.z - bf2f(h.z)), f2bf(v.w - bf2f(h.w)) };
        *(ushort4*)&cl_[tb] = lo;
    }
    #pragma unroll
    for (int off = 1; off <= 8; off <<= 1) ssq += __shfl_xor(ssq, off);
    if (f == 0) halfsq[code] = 0.5f * ssq;
}

// ---------- GEMM1 special: BM=128, BN=128, 2 blocks/CU (r21 form: dbuf, 2-barrier) ----------
__global__ __launch_bounds__(512, 2) void k_gemm1(
    const unsigned short* __restrict__ At, const unsigned short* __restrict__ Atl,
    int a_nkt,
    const unsigned short* __restrict__ Bh, const unsigned short* __restrict__ Bl,
    int b_nkt, int K,
    const float* __restrict__ bias,
    unsigned short* __restrict__ outt, unsigned short* __restrict__ outt2,
    int out_nkt)
{
    constexpr int BUFSZ = 16384;
    __shared__ __align__(16) unsigned short s_mem[2 * BUFSZ];

    const int t = threadIdx.x;
    const int id = blockIdx.x;
    const int m_low = id & 7, rest = id >> 3;
    const int nb = rest & 15;
    const int m0 = (((rest >> 4) << 3) | m_low) * 128;
    const int nb0 = nb * 128;
    const int lane = t & 63, wv = t >> 6;
    const int wm = wv >> 2, wn = wv & 3;
    const int g = lane >> 4, rr = lane & 15;
    const int nt = K >> 6;

    f32x4 acc[4][2];
    #pragma unroll
    for (int mi = 0; mi < 4; ++mi)
        #pragma unroll
        for (int ni = 0; ni < 2; ++ni) acc[mi][ni] = (f32x4){0.f, 0.f, 0.f, 0.f};

    #define G1_STAGE(buf, ktile)                                                       \
        {                                                                              \
            unsigned short* base_ = &s_mem[(buf) * BUFSZ];                             \
            const size_t ga_ = ((size_t)(m0 / 16 + wv) * a_nkt + (ktile)) * 1024;      \
            const size_t gb_ = ((size_t)((nb0 >> 4) + wv) * b_nkt + (ktile)) * 1024;   \
            _Pragma("unroll")                                                          \
            for (int hf = 0; hf < 2; ++hf) {                                           \
                gload16(At + ga_ + hf * 512 + lane * 8, base_ + wv * 1024 + hf * 512); \
                gload16(Bh + gb_ + hf * 512 + lane * 8, base_ + 8192 + wv * 1024 + hf * 512); \
            }                                                                          \
        }

    #define G1_COMPUTE(buf, ktile)                                                     \
        {                                                                              \
            const unsigned short* base_ = &s_mem[(buf) * BUFSZ];                       \
            __builtin_amdgcn_s_setprio(1);                                             \
            _Pragma("unroll")                                                          \
            for (int s = 0; s < 2; ++s) {                                              \
                const int kb = (s << 2) + g;                                           \
                bf16x8 a_h[4], a_l[4], b_h[2], b_l[2];                                 \
                _Pragma("unroll")                                                      \
                for (int i = 0; i < 4; ++i) {                                          \
                    int aaddr = (wm * 4 + i) * 1024 + kb * 128 + (rr << 3);            \
                    a_h[i] = *(const bf16x8*)&base_[aaddr];                            \
                    a_l[i] = *(const bf16x8*)(Atl +                                    \
                        ((size_t)(m0 / 16 + wm * 4 + i) * a_nkt + (ktile)) * 1024      \
                        + kb * 128 + (rr << 3));                                       \
                }                                                                      \
                _Pragma("unroll")                                                      \
                for (int j = 0; j < 2; ++j) {                                          \
                    int baddr = 8192 + (wn * 2 + j) * 1024 + kb * 128 + (rr << 3);     \
                    b_h[j] = *(const bf16x8*)&base_[baddr];                            \
                    b_l[j] = *(const bf16x8*)(Bl +                                     \
                        ((size_t)((nb0 >> 4) + wn * 2 + j) * b_nkt + (ktile)) * 1024   \
                        + kb * 128 + (rr << 3));                                       \
                }                                                                      \
                _Pragma("unroll")                                                      \
                for (int mi = 0; mi < 4; ++mi)                                         \
                    _Pragma("unroll")                                                  \
                    for (int ni = 0; ni < 2; ++ni) {                                   \
                        acc[mi][ni] = __builtin_amdgcn_mfma_f32_16x16x32_bf16(a_h[mi], b_h[ni], acc[mi][ni], 0, 0, 0); \
                        acc[mi][ni] = __builtin_amdgcn_mfma_f32_16x16x32_bf16(a_l[mi], b_h[ni], acc[mi][ni], 0, 0, 0); \
                        acc[mi][ni] = __builtin_amdgcn_mfma_f32_16x16x32_bf16(a_h[mi], b_l[ni], acc[mi][ni], 0, 0, 0); \
                    }                                                                  \
            }                                                                          \
            __builtin_amdgcn_s_setprio(0);                                             \
        }

    G1_STAGE(0, 0)
    asm volatile("s_waitcnt vmcnt(0)" ::: "memory");
    __builtin_amdgcn_s_barrier();
    __builtin_amdgcn_sched_barrier(0);

    int cur = 0;
    for (int kt = 0; kt < nt; ++kt) {
        if (kt + 1 < nt) G1_STAGE(cur ^ 1, kt + 1)
        G1_COMPUTE(cur, kt)
        asm volatile("s_waitcnt vmcnt(0)" ::: "memory");
        __builtin_amdgcn_s_barrier();
        __builtin_amdgcn_sched_barrier(0);
        cur ^= 1;
    }
    #undef G1_STAGE
    #undef G1_COMPUTE

    for (int pass = 0; pass < 2; ++pass) {
        #pragma unroll
        for (int mi = 0; mi < 4; ++mi)
            #pragma unroll
            for (int ni = 0; ni < 2; ++ni) {
                const int c = wn * 32 + ni * 16 + rr;
                float bb = bias[nb0 + c];
                const int ktl = c >> 6, k = c & 63;
                #pragma unroll
                for (int rg = 0; rg < 4; ++rg) {
                    float v = fmaxf(acc[mi][ni][rg] + bb, 0.f);
                    unsigned short hi = f2bf(v);
                    unsigned short w = (pass == 0) ? hi : f2bf(v - bf2f(hi));
                    int addr = ((wm * 4 + mi) * 2 + ktl) * 1024
                             + ((k >> 3) & 7) * 128 + (g * 4 + rg) * 8 + (k & 7);
                    s_mem[addr] = w;
                }
            }
        __syncthreads();
        unsigned short* dst = (pass == 0) ? outt : outt2;
        #pragma unroll
        for (int it = 0; it < 4; ++it) {
            int f = t + (it << 9);
            int tl = f >> 7, w8 = f & 127;
            size_t gaddr = ((size_t)(m0 / 16 + (tl >> 1)) * out_nkt + (nb0 >> 6) + (tl & 1)) * 1024;
            *(float4*)(dst + gaddr + w8 * 8) = *(const float4*)&s_mem[tl * 1024 + w8 * 8];
        }
        __syncthreads();
    }
}

// ---------- GEMM2 special: BM=64, BN=256, grid=rows/64; TRIPLE buffer, 1 barrier ----------
__global__ __launch_bounds__(512, 1) void k_gemm2(
    const unsigned short* __restrict__ At, const unsigned short* __restrict__ Atl,
    int a_nkt,
    const unsigned short* __restrict__ Bh, const unsigned short* __restrict__ Bl,
    int b_nkt, int K,
    const float* __restrict__ bias, float* __restrict__ out)
{
    constexpr int BUFSZ = 24576;
    __shared__ __align__(16) unsigned short s_mem[3 * BUFSZ];   // 144 KB

    const int t = threadIdx.x;
    const int m0 = blockIdx.x * 64;
    const int lane = t & 63, wv = t >> 6;
    const int wm = wv >> 2, wn = wv & 3;
    const int g = lane >> 4, rr = lane & 15;
    const int nt = K >> 6;

    f32x4 acc[2][4];
    #pragma unroll
    for (int mi = 0; mi < 2; ++mi)
        #pragma unroll
        for (int ni = 0; ni < 4; ++ni) acc[mi][ni] = (f32x4){0.f, 0.f, 0.f, 0.f};

    #define G2_STAGE(buf, ktile)                                                       \
        {                                                                              \
            unsigned short* base_ = &s_mem[(buf) * BUFSZ];                             \
            _Pragma("unroll")                                                          \
            for (int jj = 0; jj < 2; ++jj) {                                           \
                const int j_ = wv * 2 + jj;                                            \
                const size_t gb_ = ((size_t)j_ * b_nkt + (ktile)) * 1024;              \
                _Pragma("unroll")                                                      \
                for (int hf = 0; hf < 2; ++hf)                                         \
                    gload16(Bh + gb_ + hf * 512 + lane * 8,                            \
                            base_ + 8192 + j_ * 1024 + hf * 512);                      \
            }                                                                          \
            const int at_ = wv & 3;                                                    \
            const size_t ga_ = ((size_t)(m0 / 16 + at_) * a_nkt + (ktile)) * 1024;     \
            if (wv < 4) {                                                              \
                _Pragma("unroll")                                                      \
                for (int hf = 0; hf < 2; ++hf)                                         \
                    gload16(At + ga_ + hf * 512 + lane * 8,                            \
                            base_ + at_ * 1024 + hf * 512);                            \
            } else {                                                                   \
                _Pragma("unroll")                                                      \
                for (int hf = 0; hf < 2; ++hf)                                         \
                    gload16(Atl + ga_ + hf * 512 + lane * 8,                           \
                            base_ + 4096 + at_ * 1024 + hf * 512);                     \
            }                                                                          \
        }

    #define G2_COMPUTE(buf, ktile)                                                     \
        {                                                                              \
            const unsigned short* base_ = &s_mem[(buf) * BUFSZ];                       \
            __builtin_amdgcn_s_setprio(1);                                             \
            _Pragma("unroll")                                                          \
            for (int s = 0; s < 2; ++s) {                                              \
                const int kb = (s << 2) + g;                                           \
                bf16x8 a_h[2], a_l[2], b_h[4], b_l[4];                                 \
                _Pragma("unroll")                                                      \
                for (int i = 0; i < 2; ++i) {                                          \
                    int aaddr = (wm * 2 + i) * 1024 + kb * 128 + (rr << 3);            \
                    a_h[i] = *(const bf16x8*)&base_[aaddr];                            \
                    a_l[i] = *(const bf16x8*)&base_[4096 + aaddr];                     \
                }                                                                      \
                _Pragma("unroll")                                                      \
                for (int j = 0; j < 4; ++j) {                                          \
                    int baddr = 8192 + (wn * 4 + j) * 1024 + kb * 128 + (rr << 3);     \
                    b_h[j] = *(const bf16x8*)&base_[baddr];                            \
                    b_l[j] = *(const bf16x8*)(Bl +                                     \
                        ((size_t)(wn * 4 + j) * b_nkt + (ktile)) * 1024                \
                        + kb * 128 + (rr << 3));                                       \
                }                                                                      \
                _Pragma("unroll")                                                      \
                for (int mi = 0; mi < 2; ++mi)                                         \
                    _Pragma("unroll")                                                  \
                    for (int ni = 0; ni < 4; ++ni) {                                   \
                        acc[mi][ni] = __builtin_amdgcn_mfma_f32_16x16x32_bf16(a_h[mi], b_h[ni], acc[mi][ni], 0, 0, 0); \
                        acc[mi][ni] = __builtin_amdgcn_mfma_f32_16x16x32_bf16(a_l[mi], b_h[ni], acc[mi][ni], 0, 0, 0); \
                        acc[mi][ni] = __builtin_amdgcn_mfma_f32_16x16x32_bf16(a_h[mi], b_l[ni], acc[mi][ni], 0, 0, 0); \
                    }                                                                  \
            }                                                                          \
            __builtin_amdgcn_s_setprio(0);                                             \
        }

    G2_STAGE(0, 0)
    int bufc = 0;
    for (int kt = 0; kt < nt; ++kt) {
        const int bufn = (bufc == 2) ? 0 : bufc + 1;
        if (kt + 1 < nt) {
            G2_STAGE(bufn, kt + 1)
            asm volatile("s_waitcnt vmcnt(6)" ::: "memory");
        } else {
            asm volatile("s_waitcnt vmcnt(0)" ::: "memory");
        }
        __builtin_amdgcn_s_barrier();
        __builtin_amdgcn_sched_barrier(0);
        G2_COMPUTE(bufc, kt)
        bufc = bufn;
    }
    #undef G2_STAGE
    #undef G2_COMPUTE
    __builtin_amdgcn_s_barrier();

    float* sf = (float*)s_mem;
    #pragma unroll
    for (int mi = 0; mi < 2; ++mi)
        #pragma unroll
        for (int ni = 0; ni < 4; ++ni)
            #pragma unroll
            for (int rg = 0; rg < 4; ++rg)
                sf[(wm * 32 + mi * 16 + g * 4 + rg) * 256 + wn * 64 + ni * 16 + rr] = acc[mi][ni][rg];
    __syncthreads();
    #pragma unroll
    for (int it = 0; it < 8; ++it) {
        int f = t + (it << 9);
        int r = f >> 6, c4 = (f & 63) << 2;
        float4 v = *(const float4*)&sf[r * 256 + c4];
        v.x += bias[c4 + 0]; v.y += bias[c4 + 1];
        v.z += bias[c4 + 2]; v.w += bias[c4 + 3];
        *(float4*)(out + (size_t)(m0 + r) * EMB + c4) = v;
    }
}

// ---------- MFMA layer: SPLIT -> r15 dbuf loop; !SPLIT AFMT>=1 -> triple-buffer 1-barrier ----------
template<int SPLIT, int AFMT, int OUTT>
__global__ __launch_bounds__(512, 1) void k_layer2(
    const float* __restrict__ A, const unsigned short* __restrict__ At,
    const unsigned short* __restrict__ Atl, int a_nkt,
    int lda, int K,
    const unsigned short* __restrict__ Bh, const unsigned short* __restrict__ Bl,
    int b_nkt, const float* __restrict__ bias, int biasoff,
    float* __restrict__ out, unsigned short* __restrict__ outt,
    unsigned short* __restrict__ outt2,
    int outw, int relu, int init, int ny_log2)
{
    constexpr int BUFSZ = SPLIT ? 32768 : 24576;
    constexpr int NBUF  = SPLIT ? 2 : 3;
    constexpr int AL = 8192;
    constexpr int BH = SPLIT ? 16384 : 8192;
    __shared__ __align__(16) unsigned short s_mem[NBUF * BUFSZ];

    const int t = threadIdx.x;
    const int id = blockIdx.x;
    const int m_low = id & 7, rest = id >> 3;
    const int nb = rest & ((1 << ny_log2) - 1);
    const int m0 = (((rest >> ny_log2) << 3) | m_low) * 128;
    const int nb0 = nb * 256;
    const int lane = t & 63, wv = t >> 6;
    const int wm = wv >> 2, wn = wv & 3;
    const int g = lane >> 4, rr = lane & 15;
    const int nt = K >> 6;

    f32x4 acc[4][4];
    #pragma unroll
    for (int mi = 0; mi < 4; ++mi)
        #pragma unroll
        for (int ni = 0; ni < 4; ++ni) acc[mi][ni] = (f32x4){0.f, 0.f, 0.f, 0.f};

    #define STAGE_DMA(buf, ktile)                                                      \
        {                                                                              \
            unsigned short* base_ = &s_mem[(buf) * BUFSZ];                             \
            _Pragma("unroll")                                                          \
            for (int jj = 0; jj < 2; ++jj) {                                           \
                const int j_ = wv * 2 + jj;                                            \
                const size_t gt_ = ((size_t)(nb0 / 16 + j_) * b_nkt + (ktile)) * 1024; \
                _Pragma("unroll")                                                      \
                for (int hf = 0; hf < 2; ++hf)                                         \
                    gload16(Bh + gt_ + hf * 512 + lane * 8,                            \
                            base_ + BH + j_ * 1024 + hf * 512);                        \
            }                                                                          \
            if (AFMT >= 1) {                                                           \
                const size_t ga_ = ((size_t)(m0 / 16 + wv) * a_nkt + (ktile)) * 1024;  \
                _Pragma("unroll")                                                      \
                for (int hf = 0; hf < 2; ++hf)                                         \
                    gload16(At + ga_ + hf * 512 + lane * 8,                            \
                            base_ + wv * 1024 + hf * 512);                             \
                if (AFMT == 2) {                                                       \
                    _Pragma("unroll")                                                  \
                    for (int hf = 0; hf < 2; ++hf)                                     \
                        gload16(Atl + ga_ + hf * 512 + lane * 8,                       \
                                base_ + AL + wv * 1024 + hf * 512);                    \
                }                                                                      \
            }                                                                          \
        }

    #define A_LOAD(ktile, pv)                                                          \
        {                                                                              \
            _Pragma("unroll")                                                          \
            for (int it = 0; it < 4; ++it) {                                           \
                int f_ = t + (it << 9);                                                \
                int r_ = f_ >> 4, k4_ = (f_ & 15) << 2;                                \
                pv[it] = *(const float4*)(A + (size_t)(m0 + r_) * lda + (ktile) * 64 + k4_); \
            }                                                                          \
        }

    #define A_WRITE(buf, pv)                                                           \
        {                                                                              \
            unsigned short* base_ = &s_mem[(buf) * BUFSZ];                             \
            _Pragma("unroll")                                                          \
            for (int it = 0; it < 4; ++it) {                                           \
                int f_ = t + (it << 9);                                                \
                int r_ = f_ >> 4, k4_ = (f_ & 15) << 2;                                \
                int mt_ = r_ >> 4, rl_ = r_ & 15, kb_ = k4_ >> 3, e_ = k4_ & 7;        \
                int addr_ = mt_ * 1024 + kb_ * 128 + ((rl_ ^ kb_) << 3) + e_;          \
                float4 v_ = pv[it];                                                    \
                ushort4 hi_, lo_;                                                      \
                hi_.x = f2bf(v_.x); hi_.y = f2bf(v_.y); hi_.z = f2bf(v_.z); hi_.w = f2bf(v_.w); \
                *(ushort4*)&base_[addr_] = hi_;                                        \
                if (SPLIT) {                                                           \
                    lo_.x = f2bf(v_.x - bf2f(hi_.x)); lo_.y = f2bf(v_.y - bf2f(hi_.y)); \
                    lo_.z = f2bf(v_.z - bf2f(hi_.z)); lo_.w = f2bf(v_.w - bf2f(hi_.w)); \
                    *(ushort4*)&base_[AL + addr_] = lo_;                               \
                }                                                                      \
            }                                                                          \
        }

    #define COMPUTE(buf, ktile)                                                        \
        {                                                                              \
            const unsigned short* base_ = &s_mem[(buf) * BUFSZ];                       \
            __builtin_amdgcn_s_setprio(1);                                             \
            _Pragma("unroll")                                                          \
            for (int s = 0; s < 2; ++s) {                                              \
                const int kb = (s << 2) + g;                                           \
                bf16x8 a_h[4], a_l[4], b_h[4], b_l[4];                                 \
                _Pragma("unroll")                                                      \
                for (int i = 0; i < 4; ++i) {                                          \
                    int arow = (AFMT == 0) ? (((rr ^ kb) & 15) << 3) : (rr << 3);      \
                    int aaddr = (wm * 4 + i) * 1024 + kb * 128 + arow;                 \
                    a_h[i] = *(const bf16x8*)&base_[aaddr];                            \
                    if (SPLIT) a_l[i] = *(const bf16x8*)&base_[AL + aaddr];            \
                    int baddr = (wn * 4 + i) * 1024 + kb * 128 + (rr << 3);            \
                    b_h[i] = *(const bf16x8*)&base_[BH + baddr];                       \
                    if (SPLIT)                                                         \
                        b_l[i] = *(const bf16x8*)(Bl +                                 \
                            ((size_t)(nb0 / 16 + wn * 4 + i) * b_nkt + (ktile)) * 1024 \
                            + kb * 128 + (rr << 3));                                   \
                }                                                                      \
                _Pragma("unroll")                                                      \
                for (int mi = 0; mi < 4; ++mi)                                         \
                    _Pragma("unroll")                                                  \
                    for (int ni = 0; ni < 4; ++ni) {                                   \
                        acc[mi][ni] = __builtin_amdgcn_mfma_f32_16x16x32_bf16(a_h[mi], b_h[ni], acc[mi][ni], 0, 0, 0); \
                        if (SPLIT) {                                                   \
                            acc[mi][ni] = __builtin_amdgcn_mfma_f32_16x16x32_bf16(a_l[mi], b_h[ni], acc[mi][ni], 0, 0, 0); \
                            acc[mi][ni] = __builtin_amdgcn_mfma_f32_16x16x32_bf16(a_h[mi], b_l[ni], acc[mi][ni], 0, 0, 0); \
                        }                                                              \
                    }                                                                  \
            }                                                                          \
            __builtin_amdgcn_s_setprio(0);                                             \
        }

    if (SPLIT || AFMT == 0) {
        float4 pv[4];
        STAGE_DMA(0, 0)
        if (AFMT == 0) {
            A_LOAD(0, pv)
            A_WRITE(0, pv)
        }
        asm volatile("s_waitcnt vmcnt(0) lgkmcnt(0)" ::: "memory");
        __builtin_amdgcn_s_barrier();
        __builtin_amdgcn_sched_barrier(0);
        int cur = 0;
        for (int kt = 0; kt < nt; ++kt) {
            if (kt + 1 < nt) {
                STAGE_DMA(cur ^ 1, kt + 1)
                if (AFMT == 0) A_LOAD(kt + 1, pv)
            }
            COMPUTE(cur, kt)
            if (AFMT == 0) { if (kt + 1 < nt) A_WRITE(cur ^ 1, pv) }
            asm volatile("s_waitcnt vmcnt(0) lgkmcnt(0)" ::: "memory");
            __builtin_amdgcn_s_barrier();
            __builtin_amdgcn_sched_barrier(0);
            cur ^= 1;
        }
    } else {
        STAGE_DMA(0, 0)
        int bufc = 0;
        for (int kt = 0; kt < nt; ++kt) {
            const int bufn = (bufc == 2) ? 0 : bufc + 1;
            if (kt + 1 < nt) {
                STAGE_DMA(bufn, kt + 1)
                asm volatile("s_waitcnt vmcnt(6)" ::: "memory");
            } else {
                asm volatile("s_waitcnt vmcnt(0)" ::: "memory");
            }
            __builtin_amdgcn_s_barrier();
            __builtin_amdgcn_sched_barrier(0);
            COMPUTE(bufc, kt)
            bufc = bufn;
        }
        __builtin_amdgcn_s_barrier();
    }
    #undef STAGE_DMA
    #undef A_LOAD
    #undef A_WRITE
    #undef COMPUTE

    if (OUTT == 0) {
        float* sf = (float*)s_mem;
        for (int rm = 0; rm < 2; ++rm) {
            if (wm == rm) {
                #pragma unroll
                for (int mi = 0; mi < 4; ++mi)
                    #pragma unroll
                    for (int ni = 0; ni < 4; ++ni)
                        #pragma unroll
                        for (int rg = 0; rg < 4; ++rg)
                            sf[(mi * 16 + g * 4 + rg) * 256 + wn * 64 + ni * 16 + rr] = acc[mi][ni][rg];
            }
            __syncthreads();
            #pragma unroll
            for (int it = 0; it < 8; ++it) {
                int f = t + (it << 9);
                int r = f >> 6, c4 = (f & 63) << 2;
                float4 v = *(const float4*)&sf[r * 256 + c4];
                int gr = m0 + rm * 64 + r, gc = nb0 + c4;
                float* op = out + (size_t)gr * outw + gc;
                if (init) {
                    v.x += bias[biasoff + gc + 0]; v.y += bias[biasoff + gc + 1];
                    v.z += bias[biasoff + gc + 2]; v.w += bias[biasoff + gc + 3];
                } else {
                    float4 o = *(const float4*)op;
                    v.x += o.x; v.y += o.y; v.z += o.z; v.w += o.w;
                }
                if (relu) {
                    v.x = fmaxf(v.x, 0.f); v.y = fmaxf(v.y, 0.f);
                    v.z = fmaxf(v.z, 0.f); v.w = fmaxf(v.w, 0.f);
                }
                *(float4*)op = v;
            }
            __syncthreads();
        }
    } else {
        const int npass = (OUTT == 2) ? 2 : 1;
        for (int pass = 0; pass < npass; ++pass) {
            #pragma unroll
            for (int mi = 0; mi < 4; ++mi)
                #pragma unroll
                for (int ni = 0; ni < 4; ++ni) {
                    const int c = wn * 64 + ni * 16 + rr;
                    float bb = bias[biasoff + nb0 + c];
                    #pragma unroll
                    for (int rg = 0; rg < 4; ++rg) {
                        float v = acc[mi][ni][rg] + bb;
                        if (relu) v = fmaxf(v, 0.f);
                        unsigned short hi = f2bf(v);
                        unsigned short w = (pass == 0) ? hi : f2bf(v - bf2f(hi));
                        int addr = ((wm * 4 + mi) * 4 + wn) * 1024
                                 + (ni * 2 + (rr >> 3)) * 128 + (g * 4 + rg) * 8 + (rr & 7);
                        s_mem[addr] = w;
                    }
                }
            __syncthreads();
            unsigned short* dst = (pass == 0) ? outt : outt2;
            #pragma unroll
            for (int it = 0; it < 8; ++it) {
                int f = t + (it << 9);
                int tl = f >> 7, w8 = f & 127;
                size_t gaddr = ((size_t)(m0 / 16 + (tl >> 2)) * outw + nb0 / 64 + (tl & 3)) * 1024;
                *(float4*)(dst + gaddr + w8 * 8) = *(const float4*)&s_mem[tl * 1024 + w8 * 8];
            }
            __syncthreads();
        }
    }
}

// ---------- distance argmin v8 (r20): TRIPLE-buffered scan, ONE barrier per chunk ----------
__global__ __launch_bounds__(512, 1) void k_dist(
    float* encq, const unsigned short* __restrict__ ch,
    const unsigned short* __restrict__ cl,
    const float* __restrict__ hsq, const float* __restrict__ cb,
    unsigned short* __restrict__ qt)
{
    __shared__ __align__(16) unsigned short s_cb[3][16384];   // 96 KB
    __shared__ int s_c1[256], s_c2[256];

    const int t = threadIdx.x;
    const int lane = t & 63, wv = t >> 6;
    const int g = lane >> 4, rr = lane & 15;
    const int r0 = blockIdx.x * 256;

    bf16x8 eh[2][8], el[2][8];
    #pragma unroll
    for (int rg = 0; rg < 2; ++rg) {
        const float* ep = encq + (size_t)(r0 + wv * 32 + rg * 16 + rr) * EMB + g * 8;
        #pragma unroll
        for (int s = 0; s < 8; ++s) {
            float4 v0 = *(const float4*)(ep + s * 32);
            float4 v1 = *(const float4*)(ep + s * 32 + 4);
            float vv[8] = {v0.x, v0.y, v0.z, v0.w, v1.x, v1.y, v1.z, v1.w};
            bf16x8 a, b;
            #pragma unroll
            for (int j = 0; j < 8; ++j) {
                unsigned short h = f2bf(vv[j]);
                a[j] = (short)h;
                b[j] = (short)f2bf(vv[j] - bf2f(h));
            }
            eh[rg][s] = a; el[rg][s] = b;
        }
    }
    float b1v[2][4], b2v[2][4]; int i1v[2][4], i2v[2][4];
    #pragma unroll
    for (int rg = 0; rg < 2; ++rg)
        #pragma unroll
        for (int r2 = 0; r2 < 4; ++r2) {
            b1v[rg][r2] = -1e30f; b2v[rg][r2] = -1e30f;
            i1v[rg][r2] = 0; i2v[rg][r2] = 0;
        }

    #define STAGE(buf, c)                                                              \
        {                                                                              \
            const unsigned short* gh_ = ch + (size_t)(c) * 8192 + wv * 1024;           \
            const unsigned short* gl_ = cl + (size_t)(c) * 8192 + wv * 1024;           \
            _Pragma("unroll")                                                          \
            for (int i_ = 0; i_ < 2; ++i_) {                                           \
                gload16(gh_ + i_ * 512 + lane * 8, &s_cb[buf][wv * 1024 + i_ * 512]);  \
                gload16(gl_ + i_ * 512 + lane * 8, &s_cb[buf][8192 + wv * 1024 + i_ * 512]); \
            }                                                                          \
        }

    #define COMPUTE(cur, c, hv_)                                                       \
        {                                                                              \
            f32x4 ahh[2][2], ahl[2][2], alh[2][2];                                     \
            _Pragma("unroll")                                                          \
            for (int rg = 0; rg < 2; ++rg)                                             \
                _Pragma("unroll")                                                      \
                for (int ci = 0; ci < 2; ++ci) {                                       \
                    ahh[rg][ci] = (f32x4){0.f, 0.f, 0.f, 0.f};                         \
                    ahl[rg][ci] = (f32x4){0.f, 0.f, 0.f, 0.f};                         \
                    alh[rg][ci] = (f32x4){0.f, 0.f, 0.f, 0.f};                         \
                }                                                                      \
            __builtin_amdgcn_s_setprio(1);                                             \
            _Pragma("unroll")                                                          \
            for (int s = 0; s < 8; ++s) {                                              \
                const int ktile = s >> 1, kb = ((s & 1) << 2) + g;                     \
                _Pragma("unroll")                                                      \
                for (int ci = 0; ci < 2; ++ci) {                                       \
                    const int off = (ci * 4 + ktile) * 1024 + kb * 128 + rr * 8;       \
                    bf16x8 bh = *(const bf16x8*)&s_cb[cur][off];                       \
                    bf16x8 bl = *(const bf16x8*)&s_cb[cur][8192 + off];                \
                    _Pragma("unroll")                                                  \
                    for (int rg = 0; rg < 2; ++rg) {                                   \
                        ahh[rg][ci] = __builtin_amdgcn_mfma_f32_16x16x32_bf16(eh[rg][s], bh, ahh[rg][ci], 0, 0, 0); \
                        ahl[rg][ci] = __builtin_amdgcn_mfma_f32_16x16x32_bf16(eh[rg][s], bl, ahl[rg][ci], 0, 0, 0); \
                        alh[rg][ci] = __builtin_amdgcn_mfma_f32_16x16x32_bf16(el[rg][s], bh, alh[rg][ci], 0, 0, 0); \
                    }                                                                  \
                }                                                                      \
            }                                                                          \
            __builtin_amdgcn_s_setprio(0);                                             \
            _Pragma("unroll")                                                          \
            for (int rg = 0; rg < 2; ++rg)                                             \
                _Pragma("unroll")                                                      \
                for (int ci = 0; ci < 2; ++ci) {                                       \
                    f32x4 av = ahh[rg][ci] + ahl[rg][ci] + alh[rg][ci];                \
                    const int code = ((c) << 5) + (ci << 4) + rr;                      \
                    const float hs = __shfl(hv_, ci * 16 + rr);                        \
                    _Pragma("unroll")                                                  \
                    for (int r2 = 0; r2 < 4; ++r2) {                                   \
                        float v = av[r2] - hs;                                         \
                        bool bt1 = (v > b1v[rg][r2]) || (v == b1v[rg][r2] && code < i1v[rg][r2]); \
                        bool bt2 = (v > b2v[rg][r2]) || (v == b2v[rg][r2] && code < i2v[rg][r2]); \
                        if (bt1) { b2v[rg][r2] = b1v[rg][r2]; i2v[rg][r2] = i1v[rg][r2]; \
                                   b1v[rg][r2] = v; i1v[rg][r2] = code; }              \
                        else if (bt2) { b2v[rg][r2] = v; i2v[rg][r2] = code; }         \
                    }                                                                  \
                }                                                                      \
        }

    STAGE(0, 0)
    int bufc = 0;
    for (int c = 0; c < 128; ++c) {
        const int bufn = (bufc == 2) ? 0 : bufc + 1;
        if (c + 1 < 128) STAGE(bufn, c + 1)
        float hv_ = hsq[(c << 5) + (lane & 31)];
        if (c + 1 < 128) asm volatile("s_waitcnt vmcnt(5)" ::: "memory");
        else             asm volatile("s_waitcnt vmcnt(0)" ::: "memory");
        __builtin_amdgcn_s_barrier();
        __builtin_amdgcn_sched_barrier(0);
        COMPUTE(bufc, c, hv_)
        bufc = bufn;
    }
    #undef STAGE
    #undef COMPUTE

    #pragma unroll
    for (int off = 1; off <= 8; off <<= 1) {
        #pragma unroll
        for (int rg = 0; rg < 2; ++rg)
            #pragma unroll
            for (int r2 = 0; r2 < 4; ++r2) {
                float ob1 = __shfl_xor(b1v[rg][r2], off), ob2 = __shfl_xor(b2v[rg][r2], off);
                int oi1 = __shfl_xor(i1v[rg][r2], off), oi2 = __shfl_xor(i2v[rg][r2], off);
                bool ofirst = (ob1 > b1v[rg][r2]) || (ob1 == b1v[rg][r2] && oi1 < i1v[rg][r2]);
                if (ofirst) {
                    bool mysec = (b1v[rg][r2] > ob2) || (b1v[rg][r2] == ob2 && i1v[rg][r2] < oi2);
                    b2v[rg][r2] = mysec ? b1v[rg][r2] : ob2; i2v[rg][r2] = mysec ? i1v[rg][r2] : oi2;
                    b1v[rg][r2] = ob1; i1v[rg][r2] = oi1;
                } else {
                    bool osec = (ob1 > b2v[rg][r2]) || (ob1 == b2v[rg][r2] && oi1 < i2v[rg][r2]);
                    b2v[rg][r2] = osec ? ob1 : b2v[rg][r2]; i2v[rg][r2] = osec ? oi1 : i2v[rg][r2];
                }
            }
    }
    if (rr == 0) {
        #pragma unroll
        for (int rg = 0; rg < 2; ++rg)
            #pragma unroll
            for (int r2 = 0; r2 < 4; ++r2) {
                int rl = wv * 32 + rg * 16 + g * 4 + r2;
                s_c1[rl] = i1v[rg][r2]; s_c2[rl] = i2v[rg][r2];
            }
    }
    __syncthreads();

    for (int rloc = 0; rloc < 32; ++rloc) {
        const int row = wv * 32 + rloc;
        const int c1 = s_c1[row], c2 = s_c2[row];
        float4 ev = *(const float4*)(encq + (size_t)(r0 + row) * EMB + lane * 4);
        float4 v1 = *(const float4*)(cb + (size_t)c1 * EMB + lane * 4);
        float4 v2 = *(const float4*)(cb + (size_t)c2 * EMB + lane * 4);
        float d1 = ev.x * v1.x + ev.y * v1.y + ev.z * v1.z + ev.w * v1.w;
        float d2 = ev.x * v2.x + ev.y * v2.y + ev.z * v2.z + ev.w * v2.w;
        #pragma unroll
        for (int off = 1; off <= 32; off <<= 1) {
            d1 += __shfl_xor(d1, off);
            d2 += __shfl_xor(d2, off);
        }
        if (lane == 0) {
            float s1 = d1 - hsq[c1], s2 = d2 - hsq[c2];
            bool keep1 = (s1 > s2) || (s1 == s2 && c1 < c2);
            s_c1[row] = keep1 ? c1 : c2;
        }
    }
    __syncthreads();
    #pragma unroll
    for (int it = 0; it < 32; ++it) {
        int f = t + (it << 9);
        int row = f >> 6, c4 = (f & 63) << 2;
        int bi = s_c1[row];
        float4 qv = *(const float4*)(cb + (size_t)bi * EMB + c4);
        const int R = r0 + row;
        *(float4*)(encq + (size_t)R * EMB + c4) = qv;
        const int k4 = c4 & 63;
        size_t qaddr = ((size_t)(R >> 4) * 4 + (c4 >> 6)) * 1024
                     + (k4 >> 3) * 128 + (R & 15) * 8 + (k4 & 7);
        ushort4 qh = { f2bf(qv.x), f2bf(qv.y), f2bf(qv.z), f2bf(qv.w) };
        *(ushort4*)&qt[qaddr] = qh;
    }
}

// ---------- fallback fp32 decoder ----------
__global__ __launch_bounds__(256) void k_dec_fb(
    const float* __restrict__ qz,
    const float* __restrict__ W3, const float* __restrict__ b3,
    const float* __restrict__ W4, const float* __restrict__ b4,
    float* __restrict__ outd) {
    __shared__ float s_q[8][EMB];
    __shared__ float s_h2[8][HID];
    const int t = threadIdx.x;
    const int row0 = blockIdx.x * 8;
    #pragma unroll
    for (int r = 0; r < 8; ++r) s_q[r][t] = qz[(size_t)(row0 + r) * EMB + t];
    __syncthreads();
    for (int gg = 0; gg < 8; ++gg) {
        const int j = (gg << 8) + t;
        float acc[8];
        #pragma unroll
        for (int r = 0; r < 8; ++r) acc[r] = 0.f;
        const float* wp = W3 + j;
        for (int e = 0; e < EMB; e += 4) {
            const float w0 = wp[(size_t)(e + 0) * HID];
            const float w1v = wp[(size_t)(e + 1) * HID];
            const float w2v = wp[(size_t)(e + 2) * HID];
            const float w3v = wp[(size_t)(e + 3) * HID];
            #pragma unroll
            for (int r = 0; r < 8; ++r) {
                const float4 qv = *reinterpret_cast<const float4*>(&s_q[r][e]);
                acc[r] = fmaf(qv.x, w0, acc[r]);
                acc[r] = fmaf(qv.y, w1v, acc[r]);
                acc[r] = fmaf(qv.z, w2v, acc[r]);
                acc[r] = fmaf(qv.w, w3v, acc[r]);
            }
        }
        const float bb = b3[j];
        #pragma unroll
        for (int r = 0; r < 8; ++r) s_h2[r][j] = fmaxf(acc[r] + bb, 0.f);
    }
    __syncthreads();
    float acc4[8][4];
    #pragma unroll
    for (int r = 0; r < 8; ++r)
        #pragma unroll
        for (int ci = 0; ci < 4; ++ci) acc4[r][ci] = 0.f;
    const float* w4p = W4 + t;
    for (int k = 0; k < HID; k += 4) {
        float wv[4][4];
        #pragma unroll
        for (int ki = 0; ki < 4; ++ki)
            #pragma unroll
            for (int ci = 0; ci < 4; ++ci)
                wv[ki][ci] = w4p[(size_t)(k + ki) * IN_DIM + (ci << 8)];
        #pragma unroll
        for (int r = 0; r < 8; ++r) {
            const float4 hv = *reinterpret_cast<const float4*>(&s_h2[r][k]);
            #pragma unroll
            for (int ci = 0; ci < 4; ++ci) {
                acc4[r][ci] = fmaf(hv.x, wv[0][ci], acc4[r][ci]);
                acc4[r][ci] = fmaf(hv.y, wv[1][ci], acc4[r][ci]);
                acc4[r][ci] = fmaf(hv.z, wv[2][ci], acc4[r][ci]);
                acc4[r][ci] = fmaf(hv.w, wv[3][ci], acc4[r][ci]);
            }
        }
    }
    #pragma unroll
    for (int ci = 0; ci < 4; ++ci) {
        const float bb = b4[(ci << 8) + t];
        #pragma unroll
        for (int r = 0; r < 8; ++r)
            outd[(size_t)(row0 + r) * IN_DIM + (ci << 8) + t] = acc4[r][ci] + bb;
    }
}

extern "C" void kernel_launch(void* const* d_in, const int* in_sizes, int n_in,
                              void* d_out, int out_size, void* d_ws, size_t ws_size,
                              hipStream_t stream) {
    const float* x  = (const float*)d_in[0];
    const float* W1 = (const float*)d_in[1];
    const float* b1 = (const float*)d_in[2];
    const float* W2 = (const float*)d_in[3];
    const float* b2 = (const float*)d_in[4];
    const float* cb = (const float*)d_in[5];
    const float* W3 = (const float*)d_in[6];
    const float* b3 = (const float*)d_in[7];
    const float* W4 = (const float*)d_in[8];
    const float* b4 = (const float*)d_in[9];

    float* outq = (float*)d_out;                       // [N,256]
    float* outd = outq + (size_t)N_ROWS * EMB;         // [N,1024]

    // scratch in the decoded-output region (dead before GEMM4 writes it)
    unsigned short* ou = (unsigned short*)outd;
    unsigned short* W1Th = ou;                         // 2M ushort
    unsigned short* W1Tl = ou + 2097152;               // 2M
    unsigned short* W2Th = ou + 4194304;               // 512K
    unsigned short* W2Tl = ou + 4718592;               // 512K
    unsigned short* cbh  = ou + 5242880;               // 1M
    unsigned short* cbl  = ou + 6291456;               // 1M
    float* halfsq = outd + 3670016;                    // 4K floats
    unsigned short* h_hi = (unsigned short*)(outd + 4194304);   // 64 MB (strip)
    unsigned short* h_lo = h_hi + 33554432;                     // 64 MB (strip)
    unsigned short* qt = (unsigned short*)(outd + 58720256);    // 32 MB, tail
    float* enc = outq;                                 // consumed by k_dist

    // d_ws: W3T (1MB) + W4T (4MB) + 64MB region (xt during encoder, h2t during decoder)
    const bool fastdec = ws_size >= (size_t)72351744;
    unsigned short* W3Th = (unsigned short*)d_ws;
    unsigned short* W4Th = W3Th + 524288;
    unsigned short* h2t  = (unsigned short*)((char*)d_ws + 5242880);
    unsigned short* xt_hi = h2t;                       // 32 MB (encoder strips)
    unsigned short* xt_lo = h2t + 16777216;            // 32 MB

    // prep: weight/codebook conversion
    k_conv_w<1><<<dim3(128, 16), 256, 0, stream>>>(W1, W1Th, W1Tl, HID, 16);
    k_conv_w<1><<<dim3(16, 32), 256, 0, stream>>>(W2, W2Th, W2Tl, EMB, 32);
    k_conv_cb<<<256, 256, 0, stream>>>(cb, cbh, cbl, halfsq);
    if (fastdec) {
        k_conv_w<0><<<dim3(128, 4), 256, 0, stream>>>(W3, W3Th, nullptr, HID, 4);
        k_conv_w<0><<<dim3(64, 32), 256, 0, stream>>>(W4, W4Th, nullptr, IN_DIM, 32);
    }
    if (fastdec) {
        for (int s = 0; s < 4; ++s) {
            k_conv_a2<<<dim3(1024, 16), 256, 0, stream>>>(
                x + (size_t)s * 16777216, xt_hi, xt_lo, IN_DIM, 16);
            k_gemm1<<<2048, 512, 0, stream>>>(
                xt_hi, xt_lo, 16, W1Th, W1Tl, 16, IN_DIM, b1, h_hi, h_lo, 32);
            k_gemm2<<<256, 512, 0, stream>>>(
                h_hi, h_lo, 32, W2Th, W2Tl, 32, HID, b2,
                enc + (size_t)s * 4194304);
        }
    } else {
        for (int q = 0; q < 4; ++q) {
            k_layer2<1, 0, 2><<<1024, 512, 0, stream>>>(
                x, nullptr, nullptr, 0, IN_DIM, IN_DIM,
                W1Th + (size_t)q * 524288, W1Tl + (size_t)q * 524288, 16,
                b1, q * 512, nullptr, h_hi, h_lo, 8, 1, 0, 1);
            k_layer2<1, 2, 0><<<512, 512, 0, stream>>>(
                nullptr, h_hi, h_lo, 8, 0, 512,
                W2Th + (size_t)q * 8192, W2Tl + (size_t)q * 8192, 32,
                b2, 0, enc, nullptr, nullptr, EMB, 0, q == 0, 0);
        }
    }
    // nearest-code + gather (writes quantized output + tiled q for the decoder)
    k_dist<<<256, 512, 0, stream>>>(enc, cbh, cbl, halfsq, cb, qt);
    // decoder: 4 m-strips, single-pass GEMM4 (triple-buffer 1-barrier loops)
    if (fastdec) {
        for (int s = 0; s < 4; ++s) {
            const size_t roff = (size_t)s * 16384;
            k_layer2<0, 1, 1><<<1024, 512, 0, stream>>>(
                nullptr, qt + (size_t)s * 4194304, nullptr, 4, 0, EMB,
                W3Th, nullptr, 4,
                b3, 0, nullptr, h2t, nullptr, 32, 1, 0, 3);
            k_layer2<0, 1, 0><<<512, 512, 0, stream>>>(
                nullptr, h2t, nullptr, 32, 0, HID,
                W4Th, nullptr, 32,
                b4, 0, outd + roff * IN_DIM, nullptr, nullptr, IN_DIM, 0, 1, 2);
        }
    } else {
        k_dec_fb<<<N_ROWS / 8, 256, 0, stream>>>(outq, W3, b3, W4, b4, outd);
    }
}